// Round 21
// baseline (102.063 us; speedup 1.0000x reference)
//
#include <hip/hip_runtime.h>
#include <stdint.h>

typedef __bf16 bf16x8 __attribute__((ext_vector_type(8)));
typedef __bf16 bf16x4 __attribute__((ext_vector_type(4)));
typedef float f32x4 __attribute__((ext_vector_type(4)));
typedef float f32x16 __attribute__((ext_vector_type(16)));
typedef unsigned short u16x8 __attribute__((ext_vector_type(8)));
typedef unsigned short u16x4 __attribute__((ext_vector_type(4)));
typedef unsigned int u32x4 __attribute__((ext_vector_type(4)));

#define MFMA16(a, b, c) __builtin_amdgcn_mfma_f32_16x16x32_bf16((a), (b), (c), 0, 0, 0)
#define MFMA32(a, b, c) __builtin_amdgcn_mfma_f32_32x32x16_bf16((a), (b), (c), 0, 0, 0)
#define EXP2(x) __builtin_amdgcn_exp2f(x)

__device__ __forceinline__ unsigned short f2bf(float f) {
    unsigned int u = __builtin_bit_cast(unsigned int, f);
    return (unsigned short)((u + 0x7fffu + ((u >> 16) & 1u)) >> 16);
}

__device__ __forceinline__ unsigned int cvtpk(float lo, float hi) {
    unsigned int r;
    asm("v_cvt_pk_bf16_f32 %0, %1, %2" : "=v"(r) : "v"(lo), "v"(hi));
    return r;
}

__device__ __forceinline__ void pl32swap(unsigned int& a, unsigned int& b) {
    asm volatile("v_permlane32_swap_b32 %0, %1" : "+v"(a), "+v"(b));
}

__device__ __forceinline__ void gl_lds16(const void* g, void* l) {
    __builtin_amdgcn_global_load_lds(
        (const __attribute__((address_space(1))) unsigned int*)g,
        (__attribute__((address_space(3))) unsigned int*)l, 16, 0, 0);
}

#define BTOK   8192
#define DMODEL 512
#define NQKV   1536
#define QKSTR  1024              // compacted Q|K row stride
#define SEQ    2048
#define NH     8
#define DH     64
#define QSCL   0.18033688011112043f   // 0.125 * log2(e)

// ---------------------------------------------------------------------------
// prep: blocks 0..2047 cast x to bf16 (vectorized);
// blocks 2048..2303: LDS-tiled 64x64 weight transpose (both sides coalesced)
// ---------------------------------------------------------------------------
__global__ __launch_bounds__(256) void prep_kernel(
    const float* __restrict__ x, const float* __restrict__ Wq,
    const float* __restrict__ Wkv, const float* __restrict__ Wout,
    unsigned short* __restrict__ xb, unsigned short* __restrict__ wqkv_t,
    unsigned short* __restrict__ wout_t)
{
    __shared__ float T[64][65];
    const int bid = blockIdx.x, tid = threadIdx.x;
    if (bid < 2048) {
        int64_t i8 = ((int64_t)bid * 256 + tid) * 8;
        const float* s = x + i8;
        u16x8 o8;
#pragma unroll
        for (int j = 0; j < 8; ++j) o8[j] = f2bf(s[j]);
        *(u16x8*)&xb[i8] = o8;
        return;
    }
    const int t = bid - 2048;                 // 0..255 : 32 o-tiles x 8 i-tiles
    const int o0 = (t & 31) * 64, i0 = (t >> 5) * 64;
    const float* src; int ld, c0;
    unsigned short* dst;
    int odst;
    if (o0 < 512)        { src = Wq;   ld = 512;  c0 = o0;        dst = wqkv_t; odst = o0; }
    else if (o0 < 1536)  { src = Wkv;  ld = 1024; c0 = o0 - 512;  dst = wqkv_t; odst = o0; }
    else                 { src = Wout; ld = 512;  c0 = o0 - 1536; dst = wout_t; odst = o0 - 1536; }
    const int lane = tid & 63, rg = tid >> 6;
#pragma unroll
    for (int r = 0; r < 16; ++r) {
        int il = r * 4 + rg;
        T[il][lane] = src[(int64_t)(i0 + il) * ld + c0 + lane];
    }
    __syncthreads();
#pragma unroll
    for (int r = 0; r < 16; ++r) {
        int ol = r * 4 + rg;
        dst[(int64_t)(odst + ol) * 512 + i0 + lane] = f2bf(T[lane][ol]);
    }
}

// ---------------------------------------------------------------------------
// GEMM: 128 x TN tile, 3-BUFFER RING + counted vmcnt, ONE barrier per iter:
//   iter t: STAGE(t+2 -> b[(t+2)%3])   (flies during compute)
//           compute(t, b[t%3])
//           s_waitcnt vmcnt(LPS)        (t+1's loads retired; t+2's in flight)
//           s_barrier                   (t+1 visible to all; b[(t+2)%3] was
//                                        last read 2 barriers ago -> safe)
// vs r17: __syncthreads drained the just-issued prefetch each iter (~200cy
// exposed). vs r19: that variant paid 2 barriers/iter -> regressed.
// LPS = loads/STAGE/thread = 2 + TN/64. Chunk-XOR LDS swizzle, XCD-swizzled
// grid. QSCALE: cols<512 scaled. VSPLIT: V cols transposed to vT[bh][d][n].
// ---------------------------------------------------------------------------
template <int BF16_OUT, int QSCALE, int VSPLIT, int TN>
__global__ __launch_bounds__(256) void gemm_bt(
    const unsigned short* __restrict__ A, const unsigned short* __restrict__ Bt,
    void* __restrict__ Cout, const float* __restrict__ bias,
    unsigned short* __restrict__ vT, int M, int N, int K)
{
    constexpr int WN = TN / 2;       // wave N-tile
    constexpr int NJ = TN / 32;      // N-frags per wave
    __shared__ __align__(16) unsigned short As[3][128 * 32];
    __shared__ __align__(16) unsigned short Bs[3][TN * 32];
    const int tid = threadIdx.x;
    const int lid = tid & 63, w = tid >> 6;
    const int wr = w >> 1, wc = w & 1;
    const int l16 = lid & 15, lg = lid >> 4;

    const int linear = blockIdx.y * gridDim.x + blockIdx.x;
    const int q = (gridDim.x * gridDim.y) >> 3;
    const int nb = (linear & 7) * q + (linear >> 3);
    const int m0 = (nb % gridDim.x) * 128, n0 = (nb / gridDim.x) * TN;

    int sro[2], sco[2];
#pragma unroll
    for (int s = 0; s < 2; ++s) {
        int p = s * 256 + w * 64 + lid;
        sro[s] = p >> 2;
        sco[s] = ((p & 3) ^ ((sro[s] >> 1) & 3)) * 8;
    }

    f32x4 acc[4][NJ] = {};

#define STAGEG(BUF, K0) {                                                     \
    _Pragma("unroll")                                                         \
    for (int s_ = 0; s_ < 2; ++s_)                                            \
        gl_lds16(&A[(int64_t)(m0 + sro[s_]) * K + (K0) + sco[s_]],            \
                 &As[BUF][(s_ * 256 + w * 64) * 8]);                          \
    _Pragma("unroll")                                                         \
    for (int s_ = 0; s_ < TN / 64; ++s_)                                      \
        gl_lds16(&Bt[(int64_t)(n0 + sro[s_]) * K + (K0) + sco[s_]],           \
                 &Bs[BUF][(s_ * 256 + w * 64) * 8]);                          \
    }

#define VMWAIT_LPS { if constexpr (TN == 128)                                 \
                         asm volatile("s_waitcnt vmcnt(4)" ::: "memory");     \
                     else                                                     \
                         asm volatile("s_waitcnt vmcnt(3)" ::: "memory");     \
                     __builtin_amdgcn_sched_barrier(0); }
#define VMWAIT_0   { asm volatile("s_waitcnt vmcnt(0)" ::: "memory");         \
                     __builtin_amdgcn_sched_barrier(0); }

    const int NIT = K >> 5;                   // 16 at K=512
    STAGEG(0, 0);
    STAGEG(1, 32);
    VMWAIT_LPS;                               // tile0's loads retired
    __builtin_amdgcn_s_barrier();             // tile0 visible to all waves

#pragma unroll 1
    for (int it = 0; it < NIT; ++it) {
        const int bc = it % 3;
        if (it + 2 < NIT) STAGEG((it + 2) % 3, (it + 2) << 5);

        bf16x8 af[4], bfr[NJ];
#pragma unroll
        for (int i = 0; i < 4; ++i) {
            int ra = wr * 64 + i * 16 + l16;
            af[i] = *(const bf16x8*)&As[bc][ra * 32 + ((lg ^ ((ra >> 1) & 3)) * 8)];
        }
#pragma unroll
        for (int j = 0; j < NJ; ++j) {
            int rb = wc * WN + j * 16 + l16;
            bfr[j] = *(const bf16x8*)&Bs[bc][rb * 32 + ((lg ^ ((rb >> 1) & 3)) * 8)];
        }
#pragma unroll
        for (int i = 0; i < 4; ++i)
#pragma unroll
            for (int j = 0; j < NJ; ++j)
                acc[i][j] = MFMA16(af[i], bfr[j], acc[i][j]);

        if (it + 1 < NIT) {
            if (it + 2 < NIT) VMWAIT_LPS      // t+1 retired; t+2 in flight
            else              VMWAIT_0        // last refill: drain t+1
            __builtin_amdgcn_s_barrier();     // t+1 visible; ring slot safe
        }
    }
#undef STAGEG
#undef VMWAIT_LPS
#undef VMWAIT_0

#pragma unroll
    for (int i = 0; i < 4; ++i) {
        int row = m0 + wr * 64 + i * 16 + lg * 4;
#pragma unroll
        for (int j = 0; j < NJ; ++j) {
            int col = n0 + wc * WN + j * 16 + l16;
            if (VSPLIT && col >= 1024) {
                int h = (col - 1024) >> 6, d = (col - 1024) & 63;
                int b = row >> 11, n = row & 2047;
                u16x4 o4;
#pragma unroll
                for (int e = 0; e < 4; ++e) o4[e] = f2bf(acc[i][j][e]);
                *(u16x4*)&vT[(((int64_t)(b * 8 + h) * 64 + d) << 11) + n] = o4;
            } else {
#pragma unroll
                for (int e = 0; e < 4; ++e) {
                    float v = acc[i][j][e];
                    if (QSCALE && col < 512) v *= QSCL;
                    if (BF16_OUT) {
                        int ldc = VSPLIT ? QKSTR : N;
                        ((unsigned short*)Cout)[(int64_t)(row + e) * ldc + col] = f2bf(v);
                    } else {
                        ((float*)Cout)[(int64_t)(row + e) * N + col] = v + bias[col];
                    }
                }
            }
        }
    }
}

// ---------------------------------------------------------------------------
// Flash attention (round-9 version verbatim — best measured: 52.8 us).
// Split-KV, fixed-max softmax, all-DMA staging, one __syncthreads per tile.
// ---------------------------------------------------------------------------
__global__ __launch_bounds__(256, 4) void attn_kernel(
    const unsigned short* __restrict__ qk, const unsigned short* __restrict__ vT,
    unsigned short* __restrict__ attn_out)
{
    __shared__ __align__(16) char smem[32768];

    const int tid = threadIdx.x;
    const int lid = tid & 63, w = tid >> 6;          // wave 0..3
    const int qg = w & 1, half = w >> 1;
    const int l31 = lid & 31, g = lid >> 5;

    // bijective XCD swizzle: 1024 blocks = 8 XCDs x 128
    const int bid = blockIdx.y * 32 + blockIdx.x;
    const int nb = (bid & 7) * 128 + (bid >> 3);
    const int bx = nb & 31, bh = nb >> 5;
    const int b = bh >> 3, h = bh & 7;

    const int64_t rowbase = (int64_t)b * SEQ;
    const unsigned short* qp = qk + rowbase * QKSTR + h * DH;
    const unsigned short* kp = qp + 512;
    const unsigned short* vTp = vT + ((int64_t)bh << 17);   // bh*64*2048
    const int qrow = bx * 64 + qg * 32 + l31;

    // per-half LDS (u16 units): K buf0/1 @ 0/2048, V buf0/1 @ 4096/6144
    unsigned short* Hb = (unsigned short*)smem + half * 8192;

    // per-lane DMA source offsets (paired-interleave chunk mapping)
    int koff[2], vgoff[2];
#pragma unroll
    for (int s = 0; s < 2; ++s) {
        int rK = lid >> 1, cK = (s * 2 + qg) * 2 + (lid & 1);
        koff[s] = rK * QKSTR + cK * 8;
        int dV = qg * 32 + (lid >> 1), c2 = s * 2 + (lid & 1);
        vgoff[s] = dV * 2048 + c2 * 8;
    }

    // Q fragments (pre-scaled by QSCL in gemm epilogue)
    bf16x8 qf[4];
#pragma unroll
    for (int ks = 0; ks < 4; ++ks)
        qf[ks] = *(const bf16x8*)&qp[(int64_t)qrow * QKSTR + ks * 16 + g * 8];

    f32x16 ot0 = {}, ot1 = {};
    float ssum = 0.f;

#define STAGE_K(T, BUF) {                                                     \
    const unsigned short* kpt_ = kp + (int64_t)(T) * 32 * QKSTR;              \
    unsigned short* kb_ = Hb + (BUF) * 2048;                                  \
    _Pragma("unroll")                                                         \
    for (int s_ = 0; s_ < 2; ++s_)                                            \
        gl_lds16(&kpt_[koff[s_]], &kb_[s_ * 1024 + qg * 512]); }

#define STAGE_V(T, BUF) {                                                     \
    const unsigned short* vpt_ = vTp + (T) * 32;                              \
    unsigned short* vb_ = Hb + 4096 + (BUF) * 2048;                           \
    _Pragma("unroll")                                                         \
    for (int s_ = 0; s_ < 2; ++s_)                                            \
        gl_lds16(&vpt_[vgoff[s_]], &vb_[s_ * 1024 + qg * 512]); }

    const int tb = half * 32;
    STAGE_K(tb + 0, 0);
    STAGE_V(tb + 0, 0);
    __syncthreads();

    const int NT = 32;
    for (int t = 0; t < NT; ++t) {
        const int bc = t & 1, bn = bc ^ 1;
        const bool p1 = (t + 1 < NT);

        if (p1) { STAGE_K(tb + t + 1, bn); STAGE_V(tb + t + 1, bn); }

        // QK^T: S^T[kv][q=l31] over 32 kv rows
        f32x16 st = {};
        {
            const unsigned short* kb = Hb + bc * 2048;
            __builtin_amdgcn_s_setprio(1);
#pragma unroll
            for (int ks = 0; ks < 4; ++ks) {
                bf16x8 ka = *(const bf16x8*)&kb[ks * 512 + l31 * 16 + g * 8];
                st = MFMA32(ka, qf[ks], st);
            }
            __builtin_amdgcn_s_setprio(0);
        }

        // fixed-max softmax: P = exp2(s)
#pragma unroll
        for (int r = 0; r < 16; ++r) st[r] = EXP2(st[r]);
        float p0 = (st[0] + st[1]) + (st[2] + st[3]);
        float p1v = (st[4] + st[5]) + (st[6] + st[7]);
        float p2v = (st[8] + st[9]) + (st[10] + st[11]);
        float p3v = (st[12] + st[13]) + (st[14] + st[15]);
        ssum += (p0 + p1v) + (p2v + p3v);

        // P -> B-frags in-register
        bf16x8 pf[2];
#define PFRAG(HALFI, OUT) {                                               \
        unsigned int a0 = cvtpk(st[8 * HALFI + 0], st[8 * HALFI + 1]);    \
        unsigned int a1 = cvtpk(st[8 * HALFI + 2], st[8 * HALFI + 3]);    \
        unsigned int b0 = cvtpk(st[8 * HALFI + 4], st[8 * HALFI + 5]);    \
        unsigned int b1 = cvtpk(st[8 * HALFI + 6], st[8 * HALFI + 7]);    \
        pl32swap(a0, b0); pl32swap(a1, b1);                               \
        u32x4 t_ = {a0, a1, b0, b1};                                      \
        OUT = __builtin_bit_cast(bf16x8, t_); }
        PFRAG(0, pf[0]); PFRAG(1, pf[1]);
#undef PFRAG

        // PV(t): O^T[d][q] += V^T[d][kv] * P^T[kv][q]
        {
            const unsigned short* vb = Hb + 4096 + bc * 2048;
            __builtin_amdgcn_s_setprio(1);
#pragma unroll
            for (int kstep = 0; kstep < 2; ++kstep) {
                bf16x8 va0 = *(const bf16x8*)&vb[kstep * 1024 + l31 * 16 + g * 8];
                bf16x8 va1 = *(const bf16x8*)&vb[kstep * 1024 + 512 + l31 * 16 + g * 8];
                ot0 = MFMA32(va0, pf[kstep], ot0);
                ot1 = MFMA32(va1, pf[kstep], ot1);
            }
            __builtin_amdgcn_s_setprio(0);
        }

        if (p1) __syncthreads();
    }
#undef STAGE_K
#undef STAGE_V

    ssum += __shfl_xor(ssum, 32);

    // merge halves: pure add (shared implicit max = 0)
    __syncthreads();
    float* Ob  = (float*)smem;                     // [qg][64 lanes][33]
    float* Ssb = (float*)(smem + 16896);           // [qg][64]
    if (half) {
        float* dst = Ob + (qg * 64 + lid) * 33;
#pragma unroll
        for (int r = 0; r < 16; ++r) { dst[r] = ot0[r]; dst[16 + r] = ot1[r]; }
        Ssb[qg * 64 + lid] = ssum;
    }
    __syncthreads();
    if (!half) {
        const float* src = Ob + (qg * 64 + lid) * 33;
        float inv = 1.0f / (ssum + Ssb[qg * 64 + lid]);
        unsigned short* op = attn_out + (rowbase + qrow) * 512 + h * DH;
#pragma unroll
        for (int rr = 0; rr < 4; ++rr) {
            int d0 = 8 * rr + 4 * g;
            bf16x4 o0, o1;
#pragma unroll
            for (int e = 0; e < 4; ++e) {
                o0[e] = (__bf16)((ot0[rr * 4 + e] + src[rr * 4 + e]) * inv);
                o1[e] = (__bf16)((ot1[rr * 4 + e] + src[16 + rr * 4 + e]) * inv);
            }
            *(bf16x4*)&op[d0] = o0;
            *(bf16x4*)&op[32 + d0] = o1;
        }
    }
}

// ---------------------------------------------------------------------------
extern "C" void kernel_launch(void* const* d_in, const int* in_sizes, int n_in,
                              void* d_out, int out_size, void* d_ws, size_t ws_size,
                              hipStream_t stream)
{
    const float* x    = (const float*)d_in[0];
    const float* Wq   = (const float*)d_in[2];
    const float* Wkv  = (const float*)d_in[3];
    const float* Wout = (const float*)d_in[4];
    const float* bout = (const float*)d_in[5];
    float* out = (float*)d_out;

    char* ws = (char*)d_ws;
    unsigned short* xb     = (unsigned short*)(ws);                  //  8 MB
    unsigned short* wqkv_t = (unsigned short*)(ws + 8388608);        //  1.5 MB
    unsigned short* wout_t = (unsigned short*)(ws + 9961472);        //  0.5 MB
    unsigned short* qkb    = (unsigned short*)(ws + 10485760);       // 16 MB [8192][1024]
    unsigned short* attn_o = (unsigned short*)(ws + 27262976);       //  8 MB
    unsigned short* vT     = (unsigned short*)(ws + 35651584);       //  8 MB [32][64][2048]

    prep_kernel<<<2304, 256, 0, stream>>>(x, Wq, Wkv, Wout, xb, wqkv_t, wout_t);

    dim3 g1(64, 12);
    gemm_bt<1, 1, 1, 128><<<g1, 256, 0, stream>>>(xb, wqkv_t, (void*)qkb, nullptr,
                                                  vT, BTOK, NQKV, DMODEL);

    dim3 ga(32, 32);
    attn_kernel<<<ga, 256, 0, stream>>>(qkb, vT, attn_o);

    dim3 g2(64, 8);
    gemm_bt<0, 0, 0, 64><<<g2, 256, 0, stream>>>(attn_o, wout_t, (void*)out, bout,
                                                 nullptr, BTOK, DMODEL, DMODEL);
}

// Round 22
// 100.593 us; speedup vs baseline: 1.0146x; 1.0146x over previous
//
#include <hip/hip_runtime.h>
#include <stdint.h>

typedef __bf16 bf16x8 __attribute__((ext_vector_type(8)));
typedef __bf16 bf16x4 __attribute__((ext_vector_type(4)));
typedef float f32x4 __attribute__((ext_vector_type(4)));
typedef float f32x16 __attribute__((ext_vector_type(16)));
typedef unsigned short u16x8 __attribute__((ext_vector_type(8)));
typedef unsigned short u16x4 __attribute__((ext_vector_type(4)));
typedef unsigned int u32x4 __attribute__((ext_vector_type(4)));

#define MFMA16(a, b, c) __builtin_amdgcn_mfma_f32_16x16x32_bf16((a), (b), (c), 0, 0, 0)
#define MFMA32(a, b, c) __builtin_amdgcn_mfma_f32_32x32x16_bf16((a), (b), (c), 0, 0, 0)
#define EXP2(x) __builtin_amdgcn_exp2f(x)

__device__ __forceinline__ unsigned short f2bf(float f) {
    unsigned int u = __builtin_bit_cast(unsigned int, f);
    return (unsigned short)((u + 0x7fffu + ((u >> 16) & 1u)) >> 16);
}

__device__ __forceinline__ unsigned int cvtpk(float lo, float hi) {
    unsigned int r;
    asm("v_cvt_pk_bf16_f32 %0, %1, %2" : "=v"(r) : "v"(lo), "v"(hi));
    return r;
}

__device__ __forceinline__ void pl32swap(unsigned int& a, unsigned int& b) {
    asm volatile("v_permlane32_swap_b32 %0, %1" : "+v"(a), "+v"(b));
}

__device__ __forceinline__ void gl_lds16(const void* g, void* l) {
    __builtin_amdgcn_global_load_lds(
        (const __attribute__((address_space(1))) unsigned int*)g,
        (__attribute__((address_space(3))) unsigned int*)l, 16, 0, 0);
}

#define BTOK   8192
#define DMODEL 512
#define NQKV   1536
#define QKSTR  1024              // compacted Q|K row stride
#define SEQ    2048
#define NH     8
#define DH     64
#define QSCL   0.18033688011112043f   // 0.125 * log2(e)

// ---------------------------------------------------------------------------
// prep: blocks 0..2047 cast x to bf16 (vectorized);
// blocks 2048..2303: LDS-tiled 64x64 weight transpose (both sides coalesced)
// ---------------------------------------------------------------------------
__global__ __launch_bounds__(256) void prep_kernel(
    const float* __restrict__ x, const float* __restrict__ Wq,
    const float* __restrict__ Wkv, const float* __restrict__ Wout,
    unsigned short* __restrict__ xb, unsigned short* __restrict__ wqkv_t,
    unsigned short* __restrict__ wout_t)
{
    __shared__ float T[64][65];
    const int bid = blockIdx.x, tid = threadIdx.x;
    if (bid < 2048) {
        int64_t i8 = ((int64_t)bid * 256 + tid) * 8;
        const float* s = x + i8;
        u16x8 o8;
#pragma unroll
        for (int j = 0; j < 8; ++j) o8[j] = f2bf(s[j]);
        *(u16x8*)&xb[i8] = o8;
        return;
    }
    const int t = bid - 2048;                 // 0..255 : 32 o-tiles x 8 i-tiles
    const int o0 = (t & 31) * 64, i0 = (t >> 5) * 64;
    const float* src; int ld, c0;
    unsigned short* dst;
    int odst;
    if (o0 < 512)        { src = Wq;   ld = 512;  c0 = o0;        dst = wqkv_t; odst = o0; }
    else if (o0 < 1536)  { src = Wkv;  ld = 1024; c0 = o0 - 512;  dst = wqkv_t; odst = o0; }
    else                 { src = Wout; ld = 512;  c0 = o0 - 1536; dst = wout_t; odst = o0 - 1536; }
    const int lane = tid & 63, rg = tid >> 6;
#pragma unroll
    for (int r = 0; r < 16; ++r) {
        int il = r * 4 + rg;
        T[il][lane] = src[(int64_t)(i0 + il) * ld + c0 + lane];
    }
    __syncthreads();
#pragma unroll
    for (int r = 0; r < 16; ++r) {
        int ol = r * 4 + rg;
        dst[(int64_t)(odst + ol) * 512 + i0 + lane] = f2bf(T[lane][ol]);
    }
}

// ---------------------------------------------------------------------------
// GEMM (r17 best-measured form): 2-phase double-buffered BK=32, single
// __syncthreads per iter, chunk-XOR LDS swizzle, XCD-swizzled grid.
// QSCALE: cols<512 scaled. VSPLIT: V cols transposed to vT[bh][d][n];
// Q|K compact stride 1024.
// ---------------------------------------------------------------------------
template <int BF16_OUT, int QSCALE, int VSPLIT>
__global__ __launch_bounds__(256) void gemm_bt(
    const unsigned short* __restrict__ A, const unsigned short* __restrict__ Bt,
    void* __restrict__ Cout, const float* __restrict__ bias,
    unsigned short* __restrict__ vT, int M, int N, int K)
{
    __shared__ __align__(16) unsigned short As[2][128 * 32];
    __shared__ __align__(16) unsigned short Bs[2][128 * 32];
    const int tid = threadIdx.x;
    const int lid = tid & 63, w = tid >> 6;
    const int wr = w >> 1, wc = w & 1;
    const int l16 = lid & 15, lg = lid >> 4;

    const int linear = blockIdx.y * gridDim.x + blockIdx.x;
    const int q = (gridDim.x * gridDim.y) >> 3;
    const int nb = (linear & 7) * q + (linear >> 3);
    const int m0 = (nb % gridDim.x) * 128, n0 = (nb / gridDim.x) * 128;

    int sro[2], sco[2];
#pragma unroll
    for (int s = 0; s < 2; ++s) {
        int p = s * 256 + w * 64 + lid;
        sro[s] = p >> 2;
        sco[s] = ((p & 3) ^ ((sro[s] >> 1) & 3)) * 8;
    }

    f32x4 acc[4][4] = {};

#define STAGEG(BUF, K0) {                                                     \
    _Pragma("unroll")                                                         \
    for (int s_ = 0; s_ < 2; ++s_) {                                          \
        gl_lds16(&A[(int64_t)(m0 + sro[s_]) * K + (K0) + sco[s_]],            \
                 &As[BUF][(s_ * 256 + w * 64) * 8]);                          \
        gl_lds16(&Bt[(int64_t)(n0 + sro[s_]) * K + (K0) + sco[s_]],           \
                 &Bs[BUF][(s_ * 256 + w * 64) * 8]);                          \
    } }

    const int NIT = K >> 5;
    STAGEG(0, 0);
    __syncthreads();

#pragma unroll 1
    for (int it = 0; it < NIT; ++it) {
        const int bc = it & 1, bn = bc ^ 1;
        if (it + 1 < NIT) STAGEG(bn, (it + 1) << 5);

        bf16x8 af[4], bfr[4];
#pragma unroll
        for (int i = 0; i < 4; ++i) {
            int ra = wr * 64 + i * 16 + l16;
            int rb = wc * 64 + i * 16 + l16;
            af[i]  = *(const bf16x8*)&As[bc][ra * 32 + ((lg ^ ((ra >> 1) & 3)) * 8)];
            bfr[i] = *(const bf16x8*)&Bs[bc][rb * 32 + ((lg ^ ((rb >> 1) & 3)) * 8)];
        }
#pragma unroll
        for (int i = 0; i < 4; ++i)
#pragma unroll
            for (int j = 0; j < 4; ++j)
                acc[i][j] = MFMA16(af[i], bfr[j], acc[i][j]);

        __syncthreads();
    }
#undef STAGEG

#pragma unroll
    for (int i = 0; i < 4; ++i) {
        int row = m0 + wr * 64 + i * 16 + lg * 4;
#pragma unroll
        for (int j = 0; j < 4; ++j) {
            int col = n0 + wc * 64 + j * 16 + l16;
            if (VSPLIT && col >= 1024) {
                int h = (col - 1024) >> 6, d = (col - 1024) & 63;
                int b = row >> 11, n = row & 2047;
                u16x4 o4;
#pragma unroll
                for (int e = 0; e < 4; ++e) o4[e] = f2bf(acc[i][j][e]);
                *(u16x4*)&vT[(((int64_t)(b * 8 + h) * 64 + d) << 11) + n] = o4;
            } else {
#pragma unroll
                for (int e = 0; e < 4; ++e) {
                    float v = acc[i][j][e];
                    if (QSCALE && col < 512) v *= QSCL;
                    if (BF16_OUT) {
                        int ldc = VSPLIT ? QKSTR : N;
                        ((unsigned short*)Cout)[(int64_t)(row + e) * ldc + col] = f2bf(v);
                    } else {
                        ((float*)Cout)[(int64_t)(row + e) * N + col] = v + bias[col];
                    }
                }
            }
        }
    }
}

// ---------------------------------------------------------------------------
// Flash attention (round-9 version verbatim — best measured: 52.8 us).
// Split-KV, fixed-max softmax, all-DMA staging, one __syncthreads per tile.
// ---------------------------------------------------------------------------
__global__ __launch_bounds__(256, 4) void attn_kernel(
    const unsigned short* __restrict__ qk, const unsigned short* __restrict__ vT,
    unsigned short* __restrict__ attn_out)
{
    __shared__ __align__(16) char smem[32768];

    const int tid = threadIdx.x;
    const int lid = tid & 63, w = tid >> 6;          // wave 0..3
    const int qg = w & 1, half = w >> 1;
    const int l31 = lid & 31, g = lid >> 5;

    // bijective XCD swizzle: 1024 blocks = 8 XCDs x 128
    const int bid = blockIdx.y * 32 + blockIdx.x;
    const int nb = (bid & 7) * 128 + (bid >> 3);
    const int bx = nb & 31, bh = nb >> 5;
    const int b = bh >> 3, h = bh & 7;

    const int64_t rowbase = (int64_t)b * SEQ;
    const unsigned short* qp = qk + rowbase * QKSTR + h * DH;
    const unsigned short* kp = qp + 512;
    const unsigned short* vTp = vT + ((int64_t)bh << 17);   // bh*64*2048
    const int qrow = bx * 64 + qg * 32 + l31;

    // per-half LDS (u16 units): K buf0/1 @ 0/2048, V buf0/1 @ 4096/6144
    unsigned short* Hb = (unsigned short*)smem + half * 8192;

    // per-lane DMA source offsets (paired-interleave chunk mapping)
    int koff[2], vgoff[2];
#pragma unroll
    for (int s = 0; s < 2; ++s) {
        int rK = lid >> 1, cK = (s * 2 + qg) * 2 + (lid & 1);
        koff[s] = rK * QKSTR + cK * 8;
        int dV = qg * 32 + (lid >> 1), c2 = s * 2 + (lid & 1);
        vgoff[s] = dV * 2048 + c2 * 8;
    }

    // Q fragments (pre-scaled by QSCL in gemm epilogue)
    bf16x8 qf[4];
#pragma unroll
    for (int ks = 0; ks < 4; ++ks)
        qf[ks] = *(const bf16x8*)&qp[(int64_t)qrow * QKSTR + ks * 16 + g * 8];

    f32x16 ot0 = {}, ot1 = {};
    float ssum = 0.f;

#define STAGE_K(T, BUF) {                                                     \
    const unsigned short* kpt_ = kp + (int64_t)(T) * 32 * QKSTR;              \
    unsigned short* kb_ = Hb + (BUF) * 2048;                                  \
    _Pragma("unroll")                                                         \
    for (int s_ = 0; s_ < 2; ++s_)                                            \
        gl_lds16(&kpt_[koff[s_]], &kb_[s_ * 1024 + qg * 512]); }

#define STAGE_V(T, BUF) {                                                     \
    const unsigned short* vpt_ = vTp + (T) * 32;                              \
    unsigned short* vb_ = Hb + 4096 + (BUF) * 2048;                           \
    _Pragma("unroll")                                                         \
    for (int s_ = 0; s_ < 2; ++s_)                                            \
        gl_lds16(&vpt_[vgoff[s_]], &vb_[s_ * 1024 + qg * 512]); }

    const int tb = half * 32;
    STAGE_K(tb + 0, 0);
    STAGE_V(tb + 0, 0);
    __syncthreads();

    const int NT = 32;
    for (int t = 0; t < NT; ++t) {
        const int bc = t & 1, bn = bc ^ 1;
        const bool p1 = (t + 1 < NT);

        if (p1) { STAGE_K(tb + t + 1, bn); STAGE_V(tb + t + 1, bn); }

        // QK^T: S^T[kv][q=l31] over 32 kv rows
        f32x16 st = {};
        {
            const unsigned short* kb = Hb + bc * 2048;
            __builtin_amdgcn_s_setprio(1);
#pragma unroll
            for (int ks = 0; ks < 4; ++ks) {
                bf16x8 ka = *(const bf16x8*)&kb[ks * 512 + l31 * 16 + g * 8];
                st = MFMA32(ka, qf[ks], st);
            }
            __builtin_amdgcn_s_setprio(0);
        }

        // fixed-max softmax: P = exp2(s)
#pragma unroll
        for (int r = 0; r < 16; ++r) st[r] = EXP2(st[r]);
        float p0 = (st[0] + st[1]) + (st[2] + st[3]);
        float p1v = (st[4] + st[5]) + (st[6] + st[7]);
        float p2v = (st[8] + st[9]) + (st[10] + st[11]);
        float p3v = (st[12] + st[13]) + (st[14] + st[15]);
        ssum += (p0 + p1v) + (p2v + p3v);

        // P -> B-frags in-register
        bf16x8 pf[2];
#define PFRAG(HALFI, OUT) {                                               \
        unsigned int a0 = cvtpk(st[8 * HALFI + 0], st[8 * HALFI + 1]);    \
        unsigned int a1 = cvtpk(st[8 * HALFI + 2], st[8 * HALFI + 3]);    \
        unsigned int b0 = cvtpk(st[8 * HALFI + 4], st[8 * HALFI + 5]);    \
        unsigned int b1 = cvtpk(st[8 * HALFI + 6], st[8 * HALFI + 7]);    \
        pl32swap(a0, b0); pl32swap(a1, b1);                               \
        u32x4 t_ = {a0, a1, b0, b1};                                      \
        OUT = __builtin_bit_cast(bf16x8, t_); }
        PFRAG(0, pf[0]); PFRAG(1, pf[1]);
#undef PFRAG

        // PV(t): O^T[d][q] += V^T[d][kv] * P^T[kv][q]
        {
            const unsigned short* vb = Hb + 4096 + bc * 2048;
            __builtin_amdgcn_s_setprio(1);
#pragma unroll
            for (int kstep = 0; kstep < 2; ++kstep) {
                bf16x8 va0 = *(const bf16x8*)&vb[kstep * 1024 + l31 * 16 + g * 8];
                bf16x8 va1 = *(const bf16x8*)&vb[kstep * 1024 + 512 + l31 * 16 + g * 8];
                ot0 = MFMA32(va0, pf[kstep], ot0);
                ot1 = MFMA32(va1, pf[kstep], ot1);
            }
            __builtin_amdgcn_s_setprio(0);
        }

        if (p1) __syncthreads();
    }
#undef STAGE_K
#undef STAGE_V

    ssum += __shfl_xor(ssum, 32);

    // merge halves: pure add (shared implicit max = 0)
    __syncthreads();
    float* Ob  = (float*)smem;                     // [qg][64 lanes][33]
    float* Ssb = (float*)(smem + 16896);           // [qg][64]
    if (half) {
        float* dst = Ob + (qg * 64 + lid) * 33;
#pragma unroll
        for (int r = 0; r < 16; ++r) { dst[r] = ot0[r]; dst[16 + r] = ot1[r]; }
        Ssb[qg * 64 + lid] = ssum;
    }
    __syncthreads();
    if (!half) {
        const float* src = Ob + (qg * 64 + lid) * 33;
        float inv = 1.0f / (ssum + Ssb[qg * 64 + lid]);
        unsigned short* op = attn_out + (rowbase + qrow) * 512 + h * DH;
#pragma unroll
        for (int rr = 0; rr < 4; ++rr) {
            int d0 = 8 * rr + 4 * g;
            bf16x4 o0, o1;
#pragma unroll
            for (int e = 0; e < 4; ++e) {
                o0[e] = (__bf16)((ot0[rr * 4 + e] + src[rr * 4 + e]) * inv);
                o1[e] = (__bf16)((ot1[rr * 4 + e] + src[16 + rr * 4 + e]) * inv);
            }
            *(bf16x4*)&op[d0] = o0;
            *(bf16x4*)&op[32 + d0] = o1;
        }
    }
}

// ---------------------------------------------------------------------------
extern "C" void kernel_launch(void* const* d_in, const int* in_sizes, int n_in,
                              void* d_out, int out_size, void* d_ws, size_t ws_size,
                              hipStream_t stream)
{
    const float* x    = (const float*)d_in[0];
    const float* Wq   = (const float*)d_in[2];
    const float* Wkv  = (const float*)d_in[3];
    const float* Wout = (const float*)d_in[4];
    const float* bout = (const float*)d_in[5];
    float* out = (float*)d_out;

    char* ws = (char*)d_ws;
    unsigned short* xb     = (unsigned short*)(ws);                  //  8 MB
    unsigned short* wqkv_t = (unsigned short*)(ws + 8388608);        //  1.5 MB
    unsigned short* wout_t = (unsigned short*)(ws + 9961472);        //  0.5 MB
    unsigned short* qkb    = (unsigned short*)(ws + 10485760);       // 16 MB [8192][1024]
    unsigned short* attn_o = (unsigned short*)(ws + 27262976);       //  8 MB
    unsigned short* vT     = (unsigned short*)(ws + 35651584);       //  8 MB [32][64][2048]

    prep_kernel<<<2304, 256, 0, stream>>>(x, Wq, Wkv, Wout, xb, wqkv_t, wout_t);

    dim3 g1(64, 12);
    gemm_bt<1, 1, 1><<<g1, 256, 0, stream>>>(xb, wqkv_t, (void*)qkb, nullptr,
                                             vT, BTOK, NQKV, DMODEL);

    dim3 ga(32, 32);
    attn_kernel<<<ga, 256, 0, stream>>>(qkb, vT, attn_o);

    dim3 g2(64, 4);
    gemm_bt<0, 0, 0><<<g2, 256, 0, stream>>>(attn_o, wout_t, (void*)out, bout,
                                             nullptr, BTOK, DMODEL, DMODEL);
}